// Round 6
// baseline (77.449 us; speedup 1.0000x reference)
//
#include <hip/hip_runtime.h>

#define D_DIM 1280
#define ODIM  510

typedef short bf16x8 __attribute__((ext_vector_type(8)));  // 8 bf16 = 4 VGPRs
typedef float f32x4  __attribute__((ext_vector_type(4)));
typedef unsigned uint4n __attribute__((ext_vector_type(4)));  // native vec for nontemporal builtin

// pack two fp32 -> packed bf16 pair (round-half-up)
__device__ __forceinline__ unsigned pkbf(float a, float b) {
  unsigned ua = __float_as_uint(a), ub = __float_as_uint(b);
  return ((ua + 0x8000u) >> 16) | ((ub + 0x8000u) & 0xffff0000u);
}

// Prep: Xbf = bf16(X), A0 = bf16(X*w0), A1 = bf16(X*w1).  81920 threads, 8 d's each.
// Non-temporal stores: keep plane lines out of the producing XCD's L2 (clean L3 for consumers).
__global__ __launch_bounds__(256, 1) void pcmd_prep(
    const float* __restrict__ X,        // [512][1280]
    const float* __restrict__ W,        // [2560][2] (first 1280 rows = Wp)
    unsigned short* __restrict__ Xbf,
    unsigned short* __restrict__ A0,
    unsigned short* __restrict__ A1)
{
  int t = (int)blockIdx.x * 256 + (int)threadIdx.x;   // 0..81919
  int r = t / 160;
  int c = t - r * 160;                  // 8-col group 0..159
  const float* px = X + (size_t)r * D_DIM + c * 8;
  float4 x0 = *(const float4*)px;
  float4 x1 = *(const float4*)(px + 4);
  const float* pw = W + (size_t)c * 16; // d = c*8 → W offset d*2
  float4 w0 = *(const float4*)(pw +  0);  // w0[d],w1[d],w0[d+1],w1[d+1]
  float4 w1 = *(const float4*)(pw +  4);
  float4 w2 = *(const float4*)(pw +  8);
  float4 w3 = *(const float4*)(pw + 12);
  size_t o = (size_t)r * D_DIM + c * 8;
  uint4n vx, v0, v1;
  vx.x = pkbf(x0.x, x0.y);            vx.y = pkbf(x0.z, x0.w);
  vx.z = pkbf(x1.x, x1.y);            vx.w = pkbf(x1.z, x1.w);
  v0.x = pkbf(x0.x*w0.x, x0.y*w0.z);  v0.y = pkbf(x0.z*w1.x, x0.w*w1.z);
  v0.z = pkbf(x1.x*w2.x, x1.y*w2.z);  v0.w = pkbf(x1.z*w3.x, x1.w*w3.z);
  v1.x = pkbf(x0.x*w0.y, x0.y*w0.w);  v1.y = pkbf(x0.z*w1.y, x0.w*w1.w);
  v1.z = pkbf(x1.x*w2.y, x1.y*w2.w);  v1.w = pkbf(x1.z*w3.y, x1.w*w3.w);
  __builtin_nontemporal_store(vx, (uint4n*)(Xbf + o));
  __builtin_nontemporal_store(v0, (uint4n*)(A0  + o));
  __builtin_nontemporal_store(v1, (uint4n*)(A1  + o));
}

// GEMM: 1024 blocks (32x32 grid of 16x16 output tiles), 4 waves/block split K into
// quarters (320 each), LDS reduce, one barrier. 4 blocks/CU -> 4 waves/SIMD.
// acc_k[i][j] = sum_d A_k[i,d] * Xbf[j,d]
__global__ __launch_bounds__(256, 4) void pcmd_gemm(
    const unsigned short* __restrict__ Xbf,
    const unsigned short* __restrict__ A0,
    const unsigned short* __restrict__ A1,
    const float* __restrict__ b,
    float* __restrict__ out)            // [510][510][2]
{
  __shared__ float sR[4][2][16][16];    // [wave][ch][i][j] partials, 8 KB

  const int tid  = threadIdx.x;
  const int lane = tid & 63;
  const int wv   = tid >> 6;            // K-quarter owner
  const int m    = lane & 15;
  const int quad = lane >> 4;

  const int i_base = 1 + (int)blockIdx.y * 16;
  const int j_base = 1 + (int)blockIdx.x * 16;
  int gi = i_base + m; if (gi > 511) gi = 511;   // clamp; masked at store
  int gj = j_base + m; if (gj > 511) gj = 511;

  const int k0 = wv * 320;              // this wave's K-quarter
  const unsigned short* pa0 = A0  + (size_t)gi * D_DIM + k0 + quad * 8;
  const unsigned short* pa1 = A1  + (size_t)gi * D_DIM + k0 + quad * 8;
  const unsigned short* pb  = Xbf + (size_t)gj * D_DIM + k0 + quad * 8;

  // software pipeline over 10 K-steps, prefetch distance 4
  bf16x8 ra0[4], ra1[4], rb[4];
  #pragma unroll
  for (int s = 0; s < 4; ++s) {
    ra0[s] = *(const bf16x8*)(pa0 + s * 32);
    ra1[s] = *(const bf16x8*)(pa1 + s * 32);
    rb[s]  = *(const bf16x8*)(pb  + s * 32);
  }

  f32x4 acc0 = {0.f, 0.f, 0.f, 0.f};
  f32x4 acc1 = {0.f, 0.f, 0.f, 0.f};

  #pragma unroll
  for (int s = 0; s < 10; ++s) {
    int cur = s & 3;
    bf16x8 a0 = ra0[cur], a1 = ra1[cur], bb = rb[cur];
    if (s + 4 < 10) {
      ra0[cur] = *(const bf16x8*)(pa0 + (s + 4) * 32);
      ra1[cur] = *(const bf16x8*)(pa1 + (s + 4) * 32);
      rb[cur]  = *(const bf16x8*)(pb  + (s + 4) * 32);
    }
    acc0 = __builtin_amdgcn_mfma_f32_16x16x32_bf16(a0, bb, acc0, 0, 0, 0);
    acc1 = __builtin_amdgcn_mfma_f32_16x16x32_bf16(a1, bb, acc1, 0, 0, 0);
  }

  // C/D layout: col = lane&15 (j), row = quad*4 + reg (i)  [verified m89/m91]
  #pragma unroll
  for (int r = 0; r < 4; ++r) {
    sR[wv][0][quad * 4 + r][m] = acc0[r];
    sR[wv][1][quad * 4 + r][m] = acc1[r];
  }
  __syncthreads();

  // one thread per output cell: sum 4 K-partials per channel, add bias, store float2
  const int il = tid >> 4, jl = tid & 15;
  const int i = i_base + il, j = j_base + jl;
  if (i <= ODIM && j <= ODIM) {
    float2 v;
    v.x = sR[0][0][il][jl] + sR[1][0][il][jl] + sR[2][0][il][jl] + sR[3][0][il][jl] + b[0];
    v.y = sR[0][1][il][jl] + sR[1][1][il][jl] + sR[2][1][il][jl] + sR[3][1][il][jl] + b[1];
    *(float2*)(out + ((size_t)(i - 1) * ODIM + (j - 1)) * 2) = v;
  }
}

extern "C" void kernel_launch(void* const* d_in, const int* in_sizes, int n_in,
                              void* d_out, int out_size, void* d_ws, size_t ws_size,
                              hipStream_t stream) {
  const float* X = (const float*)d_in[0];
  const float* W = (const float*)d_in[1];
  const float* b = (const float*)d_in[2];
  float* out = (float*)d_out;
  (void)in_sizes; (void)n_in; (void)out_size; (void)ws_size;

  const size_t PLANE = (size_t)512 * D_DIM;        // elements per bf16 plane
  unsigned short* Xbf = (unsigned short*)d_ws;     // 1.31 MB
  unsigned short* A0  = Xbf + PLANE;
  unsigned short* A1  = A0 + PLANE;                // 3.93 MB total in d_ws

  hipLaunchKernelGGL(pcmd_prep, dim3(320), dim3(256), 0, stream, X, W, Xbf, A0, A1);
  hipLaunchKernelGGL(pcmd_gemm, dim3(32, 32), dim3(256), 0, stream, Xbf, A0, A1, b, out);
}

// Round 7
// 73.150 us; speedup vs baseline: 1.0588x; 1.0588x over previous
//
#include <hip/hip_runtime.h>
#include <math.h>

#define D_DIM 1280
#define ODIM  510

typedef short bf16x8 __attribute__((ext_vector_type(8)));  // 8 bf16 = 4 VGPRs
typedef float f32x4  __attribute__((ext_vector_type(4)));

// pack two fp32 -> packed bf16 pair (round-half-up)
__device__ __forceinline__ unsigned pkbf(float a, float b) {
  unsigned ua = __float_as_uint(a), ub = __float_as_uint(b);
  return ((ua + 0x8000u) >> 16) | ((ub + 0x8000u) & 0xffff0000u);
}

// Prep: Xbf = bf16(X), A0 = bf16(X*w0), A1 = bf16(X*w1).  81920 threads, 8 d's each.
// Normal stores: planes stay L2-resident for the gemm (NT regressed in round 6).
__global__ __launch_bounds__(256, 1) void pcmd_prep(
    const float* __restrict__ X,        // [512][1280]
    const float* __restrict__ W,        // [2560][2] (first 1280 rows = Wp)
    unsigned short* __restrict__ Xbf,
    unsigned short* __restrict__ A0,
    unsigned short* __restrict__ A1)
{
  int t = (int)blockIdx.x * 256 + (int)threadIdx.x;   // 0..81919
  int r = t / 160;
  int c = t - r * 160;                  // 8-col group 0..159
  const float* px = X + (size_t)r * D_DIM + c * 8;
  float4 x0 = *(const float4*)px;
  float4 x1 = *(const float4*)(px + 4);
  const float* pw = W + (size_t)c * 16; // d = c*8 → W offset d*2
  float4 w0 = *(const float4*)(pw +  0);  // w0[d],w1[d],w0[d+1],w1[d+1]
  float4 w1 = *(const float4*)(pw +  4);
  float4 w2 = *(const float4*)(pw +  8);
  float4 w3 = *(const float4*)(pw + 12);
  size_t o = (size_t)r * D_DIM + c * 8;
  uint4 vx, v0, v1;
  vx.x = pkbf(x0.x, x0.y);            vx.y = pkbf(x0.z, x0.w);
  vx.z = pkbf(x1.x, x1.y);            vx.w = pkbf(x1.z, x1.w);
  v0.x = pkbf(x0.x*w0.x, x0.y*w0.z);  v0.y = pkbf(x0.z*w1.x, x0.w*w1.z);
  v0.z = pkbf(x1.x*w2.x, x1.y*w2.z);  v0.w = pkbf(x1.z*w3.x, x1.w*w3.z);
  v1.x = pkbf(x0.x*w0.y, x0.y*w0.w);  v1.y = pkbf(x0.z*w1.y, x0.w*w1.w);
  v1.z = pkbf(x1.x*w2.y, x1.y*w2.w);  v1.w = pkbf(x1.z*w3.y, x1.w*w3.w);
  *(uint4*)(Xbf + o) = vx;
  *(uint4*)(A0  + o) = v0;
  *(uint4*)(A1  + o) = v1;
}

// GEMM over the upper triangle of the 32x32 tile grid: 528 blocks, each a 16x16
// output tile; 4 waves split K into quarters, LDS reduce, one barrier. Off-diagonal
// blocks also write the transposed tile (out is exactly symmetric in i,j).
__global__ __launch_bounds__(256, 4) void pcmd_gemm(
    const unsigned short* __restrict__ Xbf,
    const unsigned short* __restrict__ A0,
    const unsigned short* __restrict__ A1,
    const float* __restrict__ b,
    float* __restrict__ out)            // [510][510][2]
{
  __shared__ float sR[4][2][16][17];    // [wave][ch][i][j] partials, padded (+1)

  // decode linear block id -> (bi, bj), bi <= bj, over n=32 rows
  const int t = (int)blockIdx.x;        // 0..527
  int bi = (int)((65.0 - sqrt(4225.0 - 8.0 * (double)t)) * 0.5);
  // exact fixup against fp edge cases
  {
    int s0 = bi * 32 - (bi * (bi - 1)) / 2;
    if (t < s0) { --bi; s0 = bi * 32 - (bi * (bi - 1)) / 2; }
    int s1 = (bi + 1) * 32 - ((bi + 1) * bi) / 2;
    if (t >= s1) { ++bi; s0 = s1; }
    // recompute start for final bi
    s0 = bi * 32 - (bi * (bi - 1)) / 2;
    bi = bi;  // bj below uses s0
    // stash start in sR? no — just compute bj here:
  }
  const int start = bi * 32 - (bi * (bi - 1)) / 2;
  const int bj = bi + (t - start);

  const int tid  = threadIdx.x;
  const int lane = tid & 63;
  const int wv   = tid >> 6;            // K-quarter owner
  const int m    = lane & 15;
  const int quad = lane >> 4;

  const int i_base = 1 + bi * 16;
  const int j_base = 1 + bj * 16;
  int gi = i_base + m; if (gi > 511) gi = 511;   // clamp; masked at store
  int gj = j_base + m; if (gj > 511) gj = 511;

  const int k0 = wv * 320;              // this wave's K-quarter
  const unsigned short* pa0 = A0  + (size_t)gi * D_DIM + k0 + quad * 8;
  const unsigned short* pa1 = A1  + (size_t)gi * D_DIM + k0 + quad * 8;
  const unsigned short* pb  = Xbf + (size_t)gj * D_DIM + k0 + quad * 8;

  // software pipeline over 10 K-steps, prefetch distance 4
  bf16x8 ra0[4], ra1[4], rb[4];
  #pragma unroll
  for (int s = 0; s < 4; ++s) {
    ra0[s] = *(const bf16x8*)(pa0 + s * 32);
    ra1[s] = *(const bf16x8*)(pa1 + s * 32);
    rb[s]  = *(const bf16x8*)(pb  + s * 32);
  }

  f32x4 acc0 = {0.f, 0.f, 0.f, 0.f};
  f32x4 acc1 = {0.f, 0.f, 0.f, 0.f};

  #pragma unroll
  for (int s = 0; s < 10; ++s) {
    int cur = s & 3;
    bf16x8 a0 = ra0[cur], a1 = ra1[cur], bb = rb[cur];
    if (s + 4 < 10) {
      ra0[cur] = *(const bf16x8*)(pa0 + (s + 4) * 32);
      ra1[cur] = *(const bf16x8*)(pa1 + (s + 4) * 32);
      rb[cur]  = *(const bf16x8*)(pb  + (s + 4) * 32);
    }
    acc0 = __builtin_amdgcn_mfma_f32_16x16x32_bf16(a0, bb, acc0, 0, 0, 0);
    acc1 = __builtin_amdgcn_mfma_f32_16x16x32_bf16(a1, bb, acc1, 0, 0, 0);
  }

  // C/D layout: col = lane&15 (j), row = quad*4 + reg (i)  [verified m89/m91]
  #pragma unroll
  for (int r = 0; r < 4; ++r) {
    sR[wv][0][quad * 4 + r][m] = acc0[r];
    sR[wv][1][quad * 4 + r][m] = acc1[r];
  }
  __syncthreads();

  const float b0 = b[0], b1 = b[1];
  const int il = tid >> 4, jl = tid & 15;

  // direct tile: cell (i_base+il, j_base+jl), coalesced over jl
  {
    const int i = i_base + il, j = j_base + jl;
    if (i <= ODIM && j <= ODIM) {
      float2 v;
      v.x = sR[0][0][il][jl] + sR[1][0][il][jl] + sR[2][0][il][jl] + sR[3][0][il][jl] + b0;
      v.y = sR[0][1][il][jl] + sR[1][1][il][jl] + sR[2][1][il][jl] + sR[3][1][il][jl] + b1;
      *(float2*)(out + ((size_t)(i - 1) * ODIM + (j - 1)) * 2) = v;
    }
  }

  // transposed tile (off-diagonal only): cell (j_base+il, i_base+jl) = tile[jl][il].
  // LDS read stride 17 → conflict-free; global store coalesced over jl.
  if (bi != bj) {
    const int i = j_base + il, j = i_base + jl;
    if (i <= ODIM && j <= ODIM) {
      float2 v;
      v.x = sR[0][0][jl][il] + sR[1][0][jl][il] + sR[2][0][jl][il] + sR[3][0][jl][il] + b0;
      v.y = sR[0][1][jl][il] + sR[1][1][jl][il] + sR[2][1][jl][il] + sR[3][1][jl][il] + b1;
      *(float2*)(out + ((size_t)(i - 1) * ODIM + (j - 1)) * 2) = v;
    }
  }
}

extern "C" void kernel_launch(void* const* d_in, const int* in_sizes, int n_in,
                              void* d_out, int out_size, void* d_ws, size_t ws_size,
                              hipStream_t stream) {
  const float* X = (const float*)d_in[0];
  const float* W = (const float*)d_in[1];
  const float* b = (const float*)d_in[2];
  float* out = (float*)d_out;
  (void)in_sizes; (void)n_in; (void)out_size; (void)ws_size;

  const size_t PLANE = (size_t)512 * D_DIM;        // elements per bf16 plane
  unsigned short* Xbf = (unsigned short*)d_ws;     // 1.31 MB
  unsigned short* A0  = Xbf + PLANE;
  unsigned short* A1  = A0 + PLANE;                // 3.93 MB total in d_ws

  hipLaunchKernelGGL(pcmd_prep, dim3(320), dim3(256), 0, stream, X, W, Xbf, A0, A1);
  hipLaunchKernelGGL(pcmd_gemm, dim3(528), dim3(256), 0, stream, Xbf, A0, A1, b, out);
}